// Round 8
// baseline (123.001 us; speedup 1.0000x reference)
//
#include <hip/hip_runtime.h>
#include <cstdint>
#include <cstddef>

typedef __bf16 bf16x8 __attribute__((ext_vector_type(8)));
typedef float f32x4 __attribute__((ext_vector_type(4)));

#define MFMA16(a, b, c) __builtin_amdgcn_mfma_f32_16x16x32_bf16(a, b, c, 0, 0, 0)

static __device__ __forceinline__ bf16x8 ld_bf16x8(const __bf16* p) {
    return *reinterpret_cast<const bf16x8*>(p);
}

static __device__ __forceinline__ void async_cp16(const __bf16* g, __bf16* l) {
    __builtin_amdgcn_global_load_lds((const __attribute__((address_space(1))) void*)g,
                                     (__attribute__((address_space(3))) void*)l, 16, 0, 0);
}

template <int N>
static __device__ __forceinline__ void wait_vmcnt() {
    asm volatile("s_waitcnt vmcnt(%0)" ::"n"(N) : "memory");
}

static __device__ __forceinline__ void barrier_pinned() {
    __builtin_amdgcn_sched_barrier(0);
    __builtin_amdgcn_s_barrier();
    __builtin_amdgcn_sched_barrier(0);
}

// ---- DPP 16-lane rotate-reduce (pure VALU, no DS pipe) ----
template <int CTRL>
static __device__ __forceinline__ float dppmv(float x) {
    return __builtin_bit_cast(float, __builtin_amdgcn_update_dpp(
        0, __builtin_bit_cast(int, x), CTRL, 0xF, 0xF, true));
}
static __device__ __forceinline__ float rmax16(float x) {
    x = fmaxf(x, dppmv<0x121>(x));
    x = fmaxf(x, dppmv<0x122>(x));
    x = fmaxf(x, dppmv<0x124>(x));
    x = fmaxf(x, dppmv<0x128>(x));
    return x;
}
static __device__ __forceinline__ float rsum16(float x) {
    x += dppmv<0x121>(x);
    x += dppmv<0x122>(x);
    x += dppmv<0x124>(x);
    x += dppmv<0x128>(x);
    return x;
}

// ---------------- f32 -> bf16 convert (8 elems/thread) ----------------
__global__ void cvt_kernel(const float* __restrict__ src, __bf16* __restrict__ dst, int n8) {
    int i = blockIdx.x * blockDim.x + threadIdx.x;
    if (i >= n8) return;
    const float4* s4 = reinterpret_cast<const float4*>(src) + (size_t)i * 2;
    float4 a = s4[0], b = s4[1];
    bf16x8 o;
    o[0] = (__bf16)a.x; o[1] = (__bf16)a.y; o[2] = (__bf16)a.z; o[3] = (__bf16)a.w;
    o[4] = (__bf16)b.x; o[5] = (__bf16)b.y; o[6] = (__bf16)b.z; o[7] = (__bf16)b.w;
    reinterpret_cast<bf16x8*>(dst)[i] = o;
}

// ---------------- transpose-convert: in [K][N] f32 -> out [N][K] bf16 ----------------
__global__ __launch_bounds__(256) void tcvt_kernel(const float* __restrict__ in,
                                                   __bf16* __restrict__ out, int K, int N) {
    __shared__ __bf16 T[64][72];
    const int k0 = blockIdx.y * 64, n0 = blockIdx.x * 64;
    const int t = threadIdx.x;
    const int col = (t & 15) << 2;
    const int rowb = t >> 4;
    #pragma unroll
    for (int i = 0; i < 4; i++) {
        int row = i * 16 + rowb;
        float4 v = *reinterpret_cast<const float4*>(&in[(size_t)(k0 + row) * N + n0 + col]);
        T[col + 0][row] = (__bf16)v.x;
        T[col + 1][row] = (__bf16)v.y;
        T[col + 2][row] = (__bf16)v.z;
        T[col + 3][row] = (__bf16)v.w;
    }
    __syncthreads();
    const int oc = (t & 7) << 3;
    const int orb = t >> 3;
    #pragma unroll
    for (int i = 0; i < 2; i++) {
        int r = i * 32 + orb;
        bf16x8 v = *reinterpret_cast<bf16x8*>(&T[r][oc]);
        *reinterpret_cast<bf16x8*>(&out[(size_t)(n0 + r) * K + k0 + oc]) = v;
    }
}

// ---------------- 3-buffer depth-2 counted-vmcnt mainloop, chunk-XOR swizzled ----------
// C(BMxBN) += A(BMxK) * Bt(BNxK)^T. 512 threads, 8 waves, BK=32.
// LDS half layout [rows][32], 64B rows; slot-chunk cs holds logical chunk
// cl = cs ^ ((row>>1)&3) (involution). Source pre-swizzled, read applies same XOR.
template <int BM, int BN, int WM, int WN>
__device__ __forceinline__ void mainloop2(const __bf16* __restrict__ A,
                                          const __bf16* __restrict__ Bt,
                                          int K, int row0, int col0,
                                          __bf16* lds,
                                          f32x4 (&acc)[BM / WM / 16][BN / WN / 16]) {
    constexpr int MR = BM / WM / 16, NR = BN / WN / 16;
    constexpr int AE = BM * 32;
    constexpr int BUFE = AE + BN * 32;
    constexpr int APW = BM / 16 / 8;
    constexpr int BPW = BN / 16 / 8;
    const int tid = threadIdx.x, l = tid & 63, w = tid >> 6;
    const int wm = w / WN, wn = w % WN;
    const int lr = l >> 2;
    const int lcs = (((l & 3) ^ ((l >> 3) & 3)) << 3);  // pre-swizzled source k-offset
    const int fr = l & 15;
    const int fc = (((l >> 4) ^ ((l >> 1) & 3)) << 3);  // swizzled read k-offset

    const size_t arow = (size_t)(row0 + lr) * K + lcs;
    const size_t brow = (size_t)(col0 + lr) * K + lcs;
    const int nt = K >> 5;

    auto stage = [&](int t, int buf) {
        const int k0 = t << 5;
        const int bb = buf * BUFE;
        #pragma unroll
        for (int j = 0; j < APW; j++) {
            const int mi = w * APW + j;
            async_cp16(A + arow + (size_t)mi * 16 * K + k0, lds + bb + mi * 512 + l * 8);
        }
        #pragma unroll
        for (int j = 0; j < BPW; j++) {
            const int ni = w * BPW + j;
            async_cp16(Bt + brow + (size_t)ni * 16 * K + k0, lds + bb + AE + ni * 512 + l * 8);
        }
    };

    stage(0, 0);
    stage(1, 1);

    const int aoff = (wm * (BM / WM) + fr) * 32 + fc;
    const int boff = AE + (wn * (BN / WN) + fr) * 32 + fc;

    int p = 0;
    for (int t = 0; t < nt; ++t) {
        if (t + 1 < nt) {
            wait_vmcnt<APW + BPW>();  // certify stage(t) fully landed (stage(t+1) in flight)
        } else {
            wait_vmcnt<0>();
        }
        barrier_pinned();
        if (t + 2 < nt) {
            int p2 = p + 2; if (p2 >= 3) p2 -= 3;
            stage(t + 2, p2);
        }
        const int cb = p * BUFE;
        bf16x8 af[MR], bfv[NR];
        #pragma unroll
        for (int m = 0; m < MR; m++) af[m] = ld_bf16x8(&lds[cb + aoff + m * 512]);
        #pragma unroll
        for (int n = 0; n < NR; n++) bfv[n] = ld_bf16x8(&lds[cb + boff + n * 512]);
        __builtin_amdgcn_s_setprio(1);
        #pragma unroll
        for (int m = 0; m < MR; m++) {
            #pragma unroll
            for (int n = 0; n < NR; n++) {
                acc[m][n] = MFMA16(af[m], bfv[n], acc[m][n]);
            }
        }
        __builtin_amdgcn_s_setprio(0);
        asm volatile("s_waitcnt lgkmcnt(0)" ::: "memory");
        __builtin_amdgcn_sched_barrier(0);
        p = (p == 2) ? 0 : p + 1;
    }
}

// ---------------- QKV GEMM: x(4096x1024) @ w_attn^T(3072x1024) + b_attn ----------------
// 512 threads, 128x128 tile, grid 24x32 = 768 blocks = 3/CU (24 waves/CU).
__global__ __launch_bounds__(512, 2) void gemm_qkv_kernel(const __bf16* __restrict__ xb,
                                                          const __bf16* __restrict__ wabt,
                                                          const float* __restrict__ bias,
                                                          __bf16* __restrict__ qb,
                                                          __bf16* __restrict__ kb,
                                                          __bf16* __restrict__ vt,
                                                          float* __restrict__ present) {
    __shared__ __bf16 lds[3 * (128 * 32 + 128 * 32)];  // 48 KB
    f32x4 acc[2][4] = {};
    const int row0 = blockIdx.y * 128, col0 = blockIdx.x * 128;
    mainloop2<128, 128, 4, 2>(xb, wabt, 1024, row0, col0, lds, acc);

    const int l = threadIdx.x & 63, w = threadIdx.x >> 6;
    const int wm = w >> 1, wn = w & 1;
    const int part = col0 >> 10;  // uniform per block: 0=q 1=k 2=v
    #pragma unroll
    for (int n = 0; n < 4; n++) {
        int col = col0 + wn * 64 + n * 16 + (l & 15);
        int hh = (col >> 6) & 15;
        int dd = col & 63;
        float bv = bias[col];
        #pragma unroll
        for (int m = 0; m < 2; m++) {
            #pragma unroll
            for (int r = 0; r < 4; r++) {
                int row = row0 + wm * 32 + m * 16 + ((l >> 4) << 2) + r;
                int bb = row >> 11, ss = row & 2047;
                float val = acc[m][n][r] + bv;
                size_t qi = (((size_t)(bb * 16 + hh)) * 2048 + ss) * 64 + dd;
                if (part == 0) {
                    qb[qi] = (__bf16)val;
                } else if (part == 1) {
                    kb[qi] = (__bf16)val;
                    present[(((size_t)((bb * 2 + 0) * 16 + hh)) * 2048 + ss) * 64 + dd] = val;
                } else {
                    vt[(((size_t)(bb * 16 + hh)) * 64 + dd) * 2048 + ss] = (__bf16)val;
                    present[(((size_t)((bb * 2 + 1) * 16 + hh)) * 2048 + ss) * 64 + dd] = val;
                }
            }
        }
    }
}

// ---------------- Proj GEMM: a(4096x1024) @ w_proj^T(1024x1024) + b_proj ----------------
__global__ __launch_bounds__(512, 2) void gemm_proj_kernel(const __bf16* __restrict__ ab,
                                                           const __bf16* __restrict__ wpbt,
                                                           const float* __restrict__ bias,
                                                           float* __restrict__ out) {
    __shared__ __bf16 lds[3 * (128 * 32 + 128 * 32)];
    f32x4 acc[2][4] = {};
    const int row0 = blockIdx.y * 128, col0 = blockIdx.x * 128;
    mainloop2<128, 128, 4, 2>(ab, wpbt, 1024, row0, col0, lds, acc);

    const int lane = threadIdx.x & 63, w = threadIdx.x >> 6;
    const int wm = w >> 1, wn = w & 1;
    #pragma unroll
    for (int n = 0; n < 4; n++) {
        int col = col0 + wn * 64 + n * 16 + (lane & 15);
        float bv = bias[col];
        #pragma unroll
        for (int m = 0; m < 2; m++) {
            #pragma unroll
            for (int r = 0; r < 4; r++) {
                int row = row0 + wm * 32 + m * 16 + ((lane >> 4) << 2) + r;
                out[(size_t)row * 1024 + col] = acc[m][n][r] + bv;
            }
        }
    }
}

// ---------------- sliding-window causal flash attention ----------------
// 4 waves/block, 16 q-rows/wave. DPP softmax, early V loads, defer-max rescale.
__global__ __launch_bounds__(256) void attn_kernel(const __bf16* __restrict__ qb,
                                                   const __bf16* __restrict__ kb,
                                                   const __bf16* __restrict__ vtb,
                                                   __bf16* __restrict__ ab) {
    __shared__ __bf16 Pls[4][16 * 40];
    const int bh = blockIdx.x >> 5;
    const int qt = blockIdx.x & 31;
    const int lane = threadIdx.x & 63, wid = threadIdx.x >> 6;
    const int q0w = qt * 64 + wid * 16;

    const __bf16* Qh = qb + (size_t)bh * 2048 * 64;
    const __bf16* Kh = kb + (size_t)bh * 2048 * 64;
    const __bf16* Vt = vtb + (size_t)bh * 64 * 2048;
    __bf16* Pw = &Pls[wid][0];

    bf16x8 qf[2];
    {
        int qr = q0w + (lane & 15);
        const __bf16* qp = Qh + (size_t)qr * 64 + ((lane >> 4) << 3);
        qf[0] = ld_bf16x8(qp);
        qf[1] = ld_bf16x8(qp + 32);
    }

    f32x4 o[4];
    #pragma unroll
    for (int dt = 0; dt < 4; dt++) o[dt] = (f32x4){0.f, 0.f, 0.f, 0.f};
    float mrun[4] = {-1e30f, -1e30f, -1e30f, -1e30f};  // log2-domain
    float srun[4] = {0.f, 0.f, 0.f, 0.f};

    const float cl2 = 0.18033688f;  // (1/sqrt(64)) * log2(e)
    int klo = q0w - 255;
    int kt0 = klo > 0 ? (klo & ~31) : 0;

    for (int kt = kt0; kt <= q0w + 15; kt += 32) {
        // ---- issue V loads early: independent of softmax, latency hides under it ----
        bf16x8 vf[4];
        #pragma unroll
        for (int dt = 0; dt < 4; dt++)
            vf[dt] = ld_bf16x8(&Vt[(size_t)(dt * 16 + (lane & 15)) * 2048 + kt + ((lane >> 4) << 3)]);
        // ---- scores for 32 keys ----
        f32x4 s[2];
        #pragma unroll
        for (int kc = 0; kc < 2; kc++) {
            int krow = kt + kc * 16 + (lane & 15);
            const __bf16* kp = Kh + (size_t)krow * 64 + ((lane >> 4) << 3);
            bf16x8 kf0 = ld_bf16x8(kp);
            bf16x8 kf1 = ld_bf16x8(kp + 32);
            f32x4 a = (f32x4){0.f, 0.f, 0.f, 0.f};
            a = MFMA16(qf[0], kf0, a);
            a = MFMA16(qf[1], kf1, a);
            s[kc] = a;
        }
        // ---- online softmax (log2-domain, DPP reduces) ----
        const bool clean = (kt >= q0w - 240) && (kt + 31 <= q0w);  // wave-uniform
        float p0v[4], p1v[4];
        if (clean) {
            float s0v[4], s1v[4], mx[4];
            #pragma unroll
            for (int r = 0; r < 4; r++) {
                s0v[r] = s[0][r] * cl2;
                s1v[r] = s[1][r] * cl2;
                mx[r] = rmax16(fmaxf(s0v[r], s1v[r]));
            }
            float grow = fmaxf(fmaxf(mx[0] - mrun[0], mx[1] - mrun[1]),
                               fmaxf(mx[2] - mrun[2], mx[3] - mrun[3]));
            if (__all(grow <= 8.f)) {
                // defer-max: keep old max, P bounded by 2^8, skip o-rescale
                #pragma unroll
                for (int r = 0; r < 4; r++) {
                    float p0 = exp2f(s0v[r] - mrun[r]);
                    float p1 = exp2f(s1v[r] - mrun[r]);
                    srun[r] += rsum16(p0 + p1);
                    p0v[r] = p0;
                    p1v[r] = p1;
                }
            } else {
                float factor[4];
                #pragma unroll
                for (int r = 0; r < 4; r++) {
                    float mn = fmaxf(mrun[r], mx[r]);
                    float f = exp2f(mrun[r] - mn);
                    float p0 = exp2f(s0v[r] - mn);
                    float p1 = exp2f(s1v[r] - mn);
                    srun[r] = srun[r] * f + rsum16(p0 + p1);
                    mrun[r] = mn;
                    factor[r] = f;
                    p0v[r] = p0;
                    p1v[r] = p1;
                }
                #pragma unroll
                for (int dt = 0; dt < 4; dt++) {
                    #pragma unroll
                    for (int r = 0; r < 4; r++) o[dt][r] *= factor[r];
                }
            }
        } else {
            float factor[4];
            #pragma unroll
            for (int r = 0; r < 4; r++) {
                int q = q0w + ((lane >> 4) << 2) + r;
                int k0i = kt + (lane & 15);
                int k1i = k0i + 16;
                bool ok0 = (k0i <= q) && (k0i > q - 256);
                bool ok1 = (k1i <= q) && (k1i > q - 256);
                float s0 = ok0 ? s[0][r] * cl2 : -1e30f;
                float s1 = ok1 ? s[1][r] * cl2 : -1e30f;
                float mx = rmax16(fmaxf(s0, s1));
                float mn = fmaxf(mrun[r], mx);
                float f = exp2f(mrun[r] - mn);
                float p0 = ok0 ? exp2f(s0 - mn) : 0.f;
                float p1 = ok1 ? exp2f(s1 - mn) : 0.f;
                srun[r] = srun[r] * f + rsum16(p0 + p1);
                mrun[r] = mn;
                factor[r] = f;
                p0v[r] = p0;
                p1v[r] = p1;
            }
            #pragma unroll
            for (int dt = 0; dt < 4; dt++) {
                #pragma unroll
                for (int r = 0; r < 4; r++) o[dt][r] *= factor[r];
            }
        }
        // ---- write P to per-wave LDS ----
        #pragma unroll
        for (int r = 0; r < 4; r++) {
            int qrow = ((lane >> 4) << 2) + r;
            Pw[qrow * 40 + (lane & 15)] = (__bf16)p0v[r];
            Pw[qrow * 40 + 16 + (lane & 15)] = (__bf16)p1v[r];
        }
        asm volatile("s_waitcnt lgkmcnt(0)" ::: "memory");
        // ---- PV ----
        bf16x8 pf = ld_bf16x8(&Pw[(lane & 15) * 40 + ((lane >> 4) << 3)]);
        #pragma unroll
        for (int dt = 0; dt < 4; dt++) {
            o[dt] = MFMA16(pf, vf[dt], o[dt]);
        }
    }

    const int bb = bh >> 4, hh = bh & 15;
    #pragma unroll
    for (int r = 0; r < 4; r++) {
        int q = q0w + ((lane >> 4) << 2) + r;
        float inv = 1.f / srun[r];
        size_t base = ((size_t)bb * 2048 + q) * 1024 + hh * 64;
        #pragma unroll
        for (int dt = 0; dt < 4; dt++) {
            ab[base + dt * 16 + (lane & 15)] = (__bf16)(o[dt][r] * inv);
        }
    }
}

// ---------------- launch ----------------
extern "C" void kernel_launch(void* const* d_in, const int* in_sizes, int n_in,
                              void* d_out, int out_size, void* d_ws, size_t ws_size,
                              hipStream_t stream) {
    const float* x = (const float*)d_in[0];
    const float* w_attn = (const float*)d_in[1];
    const float* b_attn = (const float*)d_in[2];
    const float* w_proj = (const float*)d_in[3];
    const float* b_proj = (const float*)d_in[4];

    float* out = (float*)d_out;
    float* present = out + (size_t)2 * 2048 * 1024;

    char* w = (char*)d_ws;
    __bf16* xb   = (__bf16*)(w);
    __bf16* wabt = (__bf16*)(w + 8388608);
    __bf16* wpbt = (__bf16*)(w + 14680064);
    __bf16* qb   = (__bf16*)(w + 16777216);
    __bf16* kb   = (__bf16*)(w + 25165824);
    __bf16* vt   = (__bf16*)(w + 33554432);
    __bf16* ab   = xb;

    cvt_kernel<<<2048, 256, 0, stream>>>(x, xb, 524288);
    tcvt_kernel<<<dim3(48, 16), 256, 0, stream>>>(w_attn, wabt, 1024, 3072);
    tcvt_kernel<<<dim3(16, 16), 256, 0, stream>>>(w_proj, wpbt, 1024, 1024);

    gemm_qkv_kernel<<<dim3(24, 32), 512, 0, stream>>>(xb, wabt, b_attn, qb, kb, vt, present);

    attn_kernel<<<1024, 256, 0, stream>>>(qb, kb, vt, ab);

    gemm_proj_kernel<<<dim3(8, 32), 512, 0, stream>>>(ab, wpbt, b_proj, out);
}

// Round 9
// 118.951 us; speedup vs baseline: 1.0341x; 1.0341x over previous
//
#include <hip/hip_runtime.h>
#include <cstdint>
#include <cstddef>

typedef __bf16 bf16x8 __attribute__((ext_vector_type(8)));
typedef float f32x4 __attribute__((ext_vector_type(4)));

#define MFMA16(a, b, c) __builtin_amdgcn_mfma_f32_16x16x32_bf16(a, b, c, 0, 0, 0)

static __device__ __forceinline__ bf16x8 ld_bf16x8(const __bf16* p) {
    return *reinterpret_cast<const bf16x8*>(p);
}

static __device__ __forceinline__ void async_cp16(const __bf16* g, __bf16* l) {
    __builtin_amdgcn_global_load_lds((const __attribute__((address_space(1))) void*)g,
                                     (__attribute__((address_space(3))) void*)l, 16, 0, 0);
}

template <int N>
static __device__ __forceinline__ void wait_vmcnt() {
    asm volatile("s_waitcnt vmcnt(%0)" ::"n"(N) : "memory");
}

static __device__ __forceinline__ void barrier_pinned() {
    __builtin_amdgcn_sched_barrier(0);
    __builtin_amdgcn_s_barrier();
    __builtin_amdgcn_sched_barrier(0);
}

// ---- DPP 16-lane rotate-reduce (pure VALU, no DS pipe) ----
template <int CTRL>
static __device__ __forceinline__ float dppmv(float x) {
    return __builtin_bit_cast(float, __builtin_amdgcn_update_dpp(
        0, __builtin_bit_cast(int, x), CTRL, 0xF, 0xF, true));
}
static __device__ __forceinline__ float rmax16(float x) {
    x = fmaxf(x, dppmv<0x121>(x));
    x = fmaxf(x, dppmv<0x122>(x));
    x = fmaxf(x, dppmv<0x124>(x));
    x = fmaxf(x, dppmv<0x128>(x));
    return x;
}
static __device__ __forceinline__ float rsum16(float x) {
    x += dppmv<0x121>(x);
    x += dppmv<0x122>(x);
    x += dppmv<0x124>(x);
    x += dppmv<0x128>(x);
    return x;
}

// ---------------- f32 -> bf16 convert (8 elems/thread) ----------------
__global__ void cvt_kernel(const float* __restrict__ src, __bf16* __restrict__ dst, int n8) {
    int i = blockIdx.x * blockDim.x + threadIdx.x;
    if (i >= n8) return;
    const float4* s4 = reinterpret_cast<const float4*>(src) + (size_t)i * 2;
    float4 a = s4[0], b = s4[1];
    bf16x8 o;
    o[0] = (__bf16)a.x; o[1] = (__bf16)a.y; o[2] = (__bf16)a.z; o[3] = (__bf16)a.w;
    o[4] = (__bf16)b.x; o[5] = (__bf16)b.y; o[6] = (__bf16)b.z; o[7] = (__bf16)b.w;
    reinterpret_cast<bf16x8*>(dst)[i] = o;
}

// ---------------- transpose-convert: in [K][N] f32 -> out [N][K] bf16 ----------------
__global__ __launch_bounds__(256) void tcvt_kernel(const float* __restrict__ in,
                                                   __bf16* __restrict__ out, int K, int N) {
    __shared__ __bf16 T[64][72];
    const int k0 = blockIdx.y * 64, n0 = blockIdx.x * 64;
    const int t = threadIdx.x;
    const int col = (t & 15) << 2;
    const int rowb = t >> 4;
    #pragma unroll
    for (int i = 0; i < 4; i++) {
        int row = i * 16 + rowb;
        float4 v = *reinterpret_cast<const float4*>(&in[(size_t)(k0 + row) * N + n0 + col]);
        T[col + 0][row] = (__bf16)v.x;
        T[col + 1][row] = (__bf16)v.y;
        T[col + 2][row] = (__bf16)v.z;
        T[col + 3][row] = (__bf16)v.w;
    }
    __syncthreads();
    const int oc = (t & 7) << 3;
    const int orb = t >> 3;
    #pragma unroll
    for (int i = 0; i < 2; i++) {
        int r = i * 32 + orb;
        bf16x8 v = *reinterpret_cast<bf16x8*>(&T[r][oc]);
        *reinterpret_cast<bf16x8*>(&out[(size_t)(n0 + r) * K + k0 + oc]) = v;
    }
}

// ---------------- 3-buffer depth-2 counted-vmcnt mainloop, chunk-XOR swizzled ----------
template <int BM, int BN, int WM, int WN>
__device__ __forceinline__ void mainloop2(const __bf16* __restrict__ A,
                                          const __bf16* __restrict__ Bt,
                                          int K, int row0, int col0,
                                          __bf16* lds,
                                          f32x4 (&acc)[BM / WM / 16][BN / WN / 16]) {
    constexpr int MR = BM / WM / 16, NR = BN / WN / 16;
    constexpr int AE = BM * 32;
    constexpr int BUFE = AE + BN * 32;
    constexpr int APW = BM / 16 / 8;
    constexpr int BPW = BN / 16 / 8;
    const int tid = threadIdx.x, l = tid & 63, w = tid >> 6;
    const int wm = w / WN, wn = w % WN;
    const int lr = l >> 2;
    const int lcs = (((l & 3) ^ ((l >> 3) & 3)) << 3);  // pre-swizzled source k-offset
    const int fr = l & 15;
    const int fc = (((l >> 4) ^ ((l >> 1) & 3)) << 3);  // swizzled read k-offset

    const size_t arow = (size_t)(row0 + lr) * K + lcs;
    const size_t brow = (size_t)(col0 + lr) * K + lcs;
    const int nt = K >> 5;

    auto stage = [&](int t, int buf) {
        const int k0 = t << 5;
        const int bb = buf * BUFE;
        #pragma unroll
        for (int j = 0; j < APW; j++) {
            const int mi = w * APW + j;
            async_cp16(A + arow + (size_t)mi * 16 * K + k0, lds + bb + mi * 512 + l * 8);
        }
        #pragma unroll
        for (int j = 0; j < BPW; j++) {
            const int ni = w * BPW + j;
            async_cp16(Bt + brow + (size_t)ni * 16 * K + k0, lds + bb + AE + ni * 512 + l * 8);
        }
    };

    stage(0, 0);
    stage(1, 1);

    const int aoff = (wm * (BM / WM) + fr) * 32 + fc;
    const int boff = AE + (wn * (BN / WN) + fr) * 32 + fc;

    int p = 0;
    for (int t = 0; t < nt; ++t) {
        if (t + 1 < nt) {
            wait_vmcnt<APW + BPW>();
        } else {
            wait_vmcnt<0>();
        }
        barrier_pinned();
        if (t + 2 < nt) {
            int p2 = p + 2; if (p2 >= 3) p2 -= 3;
            stage(t + 2, p2);
        }
        const int cb = p * BUFE;
        bf16x8 af[MR], bfv[NR];
        #pragma unroll
        for (int m = 0; m < MR; m++) af[m] = ld_bf16x8(&lds[cb + aoff + m * 512]);
        #pragma unroll
        for (int n = 0; n < NR; n++) bfv[n] = ld_bf16x8(&lds[cb + boff + n * 512]);
        __builtin_amdgcn_s_setprio(1);
        #pragma unroll
        for (int m = 0; m < MR; m++) {
            #pragma unroll
            for (int n = 0; n < NR; n++) {
                acc[m][n] = MFMA16(af[m], bfv[n], acc[m][n]);
            }
        }
        __builtin_amdgcn_s_setprio(0);
        asm volatile("s_waitcnt lgkmcnt(0)" ::: "memory");
        __builtin_amdgcn_sched_barrier(0);
        p = (p == 2) ? 0 : p + 1;
    }
}

// ---------------- QKV GEMM: x(4096x1024) @ w_attn^T(3072x1024) + b_attn ----------------
__global__ __launch_bounds__(512, 2) void gemm_qkv_kernel(const __bf16* __restrict__ xb,
                                                          const __bf16* __restrict__ wabt,
                                                          const float* __restrict__ bias,
                                                          __bf16* __restrict__ qb,
                                                          __bf16* __restrict__ kb,
                                                          __bf16* __restrict__ vt,
                                                          float* __restrict__ present) {
    __shared__ __bf16 lds[3 * (128 * 32 + 128 * 32)];  // 48 KB
    f32x4 acc[2][4] = {};
    const int row0 = blockIdx.y * 128, col0 = blockIdx.x * 128;
    mainloop2<128, 128, 4, 2>(xb, wabt, 1024, row0, col0, lds, acc);

    const int l = threadIdx.x & 63, w = threadIdx.x >> 6;
    const int wm = w >> 1, wn = w & 1;
    const int part = col0 >> 10;  // uniform per block: 0=q 1=k 2=v
    #pragma unroll
    for (int n = 0; n < 4; n++) {
        int col = col0 + wn * 64 + n * 16 + (l & 15);
        int hh = (col >> 6) & 15;
        int dd = col & 63;
        float bv = bias[col];
        #pragma unroll
        for (int m = 0; m < 2; m++) {
            #pragma unroll
            for (int r = 0; r < 4; r++) {
                int row = row0 + wm * 32 + m * 16 + ((l >> 4) << 2) + r;
                int bb = row >> 11, ss = row & 2047;
                float val = acc[m][n][r] + bv;
                size_t qi = (((size_t)(bb * 16 + hh)) * 2048 + ss) * 64 + dd;
                if (part == 0) {
                    qb[qi] = (__bf16)val;
                } else if (part == 1) {
                    kb[qi] = (__bf16)val;
                    present[(((size_t)((bb * 2 + 0) * 16 + hh)) * 2048 + ss) * 64 + dd] = val;
                } else {
                    vt[(((size_t)(bb * 16 + hh)) * 64 + dd) * 2048 + ss] = (__bf16)val;
                    present[(((size_t)((bb * 2 + 1) * 16 + hh)) * 2048 + ss) * 64 + dd] = val;
                }
            }
        }
    }
}

// ---------------- Proj GEMM: a(4096x1024) @ w_proj^T(1024x1024) + b_proj ----------------
__global__ __launch_bounds__(512, 2) void gemm_proj_kernel(const __bf16* __restrict__ ab,
                                                           const __bf16* __restrict__ wpbt,
                                                           const float* __restrict__ bias,
                                                           float* __restrict__ out) {
    __shared__ __bf16 lds[3 * (128 * 32 + 128 * 32)];
    f32x4 acc[2][4] = {};
    const int row0 = blockIdx.y * 128, col0 = blockIdx.x * 128;
    mainloop2<128, 128, 4, 2>(ab, wpbt, 1024, row0, col0, lds, acc);

    const int lane = threadIdx.x & 63, w = threadIdx.x >> 6;
    const int wm = w >> 1, wn = w & 1;
    #pragma unroll
    for (int n = 0; n < 4; n++) {
        int col = col0 + wn * 64 + n * 16 + (lane & 15);
        float bv = bias[col];
        #pragma unroll
        for (int m = 0; m < 2; m++) {
            #pragma unroll
            for (int r = 0; r < 4; r++) {
                int row = row0 + wm * 32 + m * 16 + ((lane >> 4) << 2) + r;
                out[(size_t)row * 1024 + col] = acc[m][n][r] + bv;
            }
        }
    }
}

// ---------------- sliding-window causal flash attention ----------------
// 4 waves/block, 16 q-rows/wave. XCD head-grouped swizzle, depth-1 K/V register
// prefetch, DPP softmax, defer-max rescale, setprio around MFMA clusters.
__global__ __launch_bounds__(256) void attn_kernel(const __bf16* __restrict__ qb,
                                                   const __bf16* __restrict__ kb,
                                                   const __bf16* __restrict__ vtb,
                                                   __bf16* __restrict__ ab) {
    __shared__ __bf16 Pls[4][16 * 40];
    // XCD-locality swizzle (xcd = blockIdx % 8 empirically): each XCD owns 4
    // whole heads (K+V = 2 MB < 4 MB L2); q-tiles sweep while windows stay hot.
    const int bidx = blockIdx.x;
    const int xcd = bidx & 7, idx = bidx >> 3;
    const int bh = (xcd << 2) | (idx & 3);
    const int qt = idx >> 2;
    const int lane = threadIdx.x & 63, wid = threadIdx.x >> 6;
    const int q0w = qt * 64 + wid * 16;

    const __bf16* Qh = qb + (size_t)bh * 2048 * 64;
    const __bf16* Kh = kb + (size_t)bh * 2048 * 64;
    const __bf16* Vt = vtb + (size_t)bh * 64 * 2048;
    __bf16* Pw = &Pls[wid][0];

    const int ld16 = lane & 15, hi3 = (lane >> 4) << 3;

    bf16x8 qf[2];
    {
        const __bf16* qp = Qh + (size_t)(q0w + ld16) * 64 + hi3;
        qf[0] = ld_bf16x8(qp);
        qf[1] = ld_bf16x8(qp + 32);
    }

    f32x4 o[4];
    #pragma unroll
    for (int dt = 0; dt < 4; dt++) o[dt] = (f32x4){0.f, 0.f, 0.f, 0.f};
    float mrun[4] = {-1e30f, -1e30f, -1e30f, -1e30f};  // log2-domain
    float srun[4] = {0.f, 0.f, 0.f, 0.f};

    const float cl2 = 0.18033688f;  // (1/sqrt(64)) * log2(e)
    int klo = q0w - 255;
    int kt0 = klo > 0 ? (klo & ~31) : 0;
    const int ktend = q0w + 15;

    // prologue: prefetch tile kt0 into registers
    bf16x8 k0a, k0b, k1a, k1b, v0, v1, v2, v3;
    {
        const __bf16* kp = Kh + (size_t)(kt0 + ld16) * 64 + hi3;
        k0a = ld_bf16x8(kp);
        k0b = ld_bf16x8(kp + 32);
        k1a = ld_bf16x8(kp + 1024);
        k1b = ld_bf16x8(kp + 1024 + 32);
        v0 = ld_bf16x8(&Vt[(size_t)(ld16) * 2048 + kt0 + hi3]);
        v1 = ld_bf16x8(&Vt[(size_t)(16 + ld16) * 2048 + kt0 + hi3]);
        v2 = ld_bf16x8(&Vt[(size_t)(32 + ld16) * 2048 + kt0 + hi3]);
        v3 = ld_bf16x8(&Vt[(size_t)(48 + ld16) * 2048 + kt0 + hi3]);
    }

    for (int kt = kt0; kt <= ktend; kt += 32) {
        // ---- issue next tile's K/V loads (latency hides under this tile's work) ----
        const bool more = (kt + 32) <= ktend;
        bf16x8 nk0a, nk0b, nk1a, nk1b, nv0, nv1, nv2, nv3;
        if (more) {
            const int ktn = kt + 32;
            const __bf16* kp = Kh + (size_t)(ktn + ld16) * 64 + hi3;
            nk0a = ld_bf16x8(kp);
            nk0b = ld_bf16x8(kp + 32);
            nk1a = ld_bf16x8(kp + 1024);
            nk1b = ld_bf16x8(kp + 1024 + 32);
            nv0 = ld_bf16x8(&Vt[(size_t)(ld16) * 2048 + ktn + hi3]);
            nv1 = ld_bf16x8(&Vt[(size_t)(16 + ld16) * 2048 + ktn + hi3]);
            nv2 = ld_bf16x8(&Vt[(size_t)(32 + ld16) * 2048 + ktn + hi3]);
            nv3 = ld_bf16x8(&Vt[(size_t)(48 + ld16) * 2048 + ktn + hi3]);
        }
        // ---- scores for 32 keys (registers) ----
        f32x4 s[2];
        __builtin_amdgcn_s_setprio(1);
        {
            f32x4 a = (f32x4){0.f, 0.f, 0.f, 0.f};
            a = MFMA16(qf[0], k0a, a);
            a = MFMA16(qf[1], k0b, a);
            s[0] = a;
        }
        {
            f32x4 a = (f32x4){0.f, 0.f, 0.f, 0.f};
            a = MFMA16(qf[0], k1a, a);
            a = MFMA16(qf[1], k1b, a);
            s[1] = a;
        }
        __builtin_amdgcn_s_setprio(0);
        // ---- online softmax (log2-domain, DPP reduces) ----
        const bool clean = (kt >= q0w - 240) && (kt + 31 <= q0w);  // wave-uniform
        float p0v[4], p1v[4];
        if (clean) {
            float s0v[4], s1v[4], mx[4];
            #pragma unroll
            for (int r = 0; r < 4; r++) {
                s0v[r] = s[0][r] * cl2;
                s1v[r] = s[1][r] * cl2;
                mx[r] = rmax16(fmaxf(s0v[r], s1v[r]));
            }
            float grow = fmaxf(fmaxf(mx[0] - mrun[0], mx[1] - mrun[1]),
                               fmaxf(mx[2] - mrun[2], mx[3] - mrun[3]));
            if (__all(grow <= 8.f)) {
                #pragma unroll
                for (int r = 0; r < 4; r++) {
                    float p0 = exp2f(s0v[r] - mrun[r]);
                    float p1 = exp2f(s1v[r] - mrun[r]);
                    srun[r] += rsum16(p0 + p1);
                    p0v[r] = p0;
                    p1v[r] = p1;
                }
            } else {
                float factor[4];
                #pragma unroll
                for (int r = 0; r < 4; r++) {
                    float mn = fmaxf(mrun[r], mx[r]);
                    float f = exp2f(mrun[r] - mn);
                    float p0 = exp2f(s0v[r] - mn);
                    float p1 = exp2f(s1v[r] - mn);
                    srun[r] = srun[r] * f + rsum16(p0 + p1);
                    mrun[r] = mn;
                    factor[r] = f;
                    p0v[r] = p0;
                    p1v[r] = p1;
                }
                #pragma unroll
                for (int dt = 0; dt < 4; dt++) {
                    #pragma unroll
                    for (int r = 0; r < 4; r++) o[dt][r] *= factor[r];
                }
            }
        } else {
            float factor[4];
            #pragma unroll
            for (int r = 0; r < 4; r++) {
                int q = q0w + ((lane >> 4) << 2) + r;
                int k0i = kt + ld16;
                int k1i = k0i + 16;
                bool ok0 = (k0i <= q) && (k0i > q - 256);
                bool ok1 = (k1i <= q) && (k1i > q - 256);
                float s0 = ok0 ? s[0][r] * cl2 : -1e30f;
                float s1 = ok1 ? s[1][r] * cl2 : -1e30f;
                float mx = rmax16(fmaxf(s0, s1));
                float mn = fmaxf(mrun[r], mx);
                float f = exp2f(mrun[r] - mn);
                float p0 = ok0 ? exp2f(s0 - mn) : 0.f;
                float p1 = ok1 ? exp2f(s1 - mn) : 0.f;
                srun[r] = srun[r] * f + rsum16(p0 + p1);
                mrun[r] = mn;
                factor[r] = f;
                p0v[r] = p0;
                p1v[r] = p1;
            }
            #pragma unroll
            for (int dt = 0; dt < 4; dt++) {
                #pragma unroll
                for (int r = 0; r < 4; r++) o[dt][r] *= factor[r];
            }
        }
        // ---- write P to per-wave LDS ----
        #pragma unroll
        for (int r = 0; r < 4; r++) {
            int qrow = ((lane >> 4) << 2) + r;
            Pw[qrow * 40 + ld16] = (__bf16)p0v[r];
            Pw[qrow * 40 + 16 + ld16] = (__bf16)p1v[r];
        }
        asm volatile("s_waitcnt lgkmcnt(0)" ::: "memory");
        // ---- PV ----
        bf16x8 pf = ld_bf16x8(&Pw[ld16 * 40 + hi3]);
        __builtin_amdgcn_s_setprio(1);
        o[0] = MFMA16(pf, v0, o[0]);
        o[1] = MFMA16(pf, v1, o[1]);
        o[2] = MFMA16(pf, v2, o[2]);
        o[3] = MFMA16(pf, v3, o[3]);
        __builtin_amdgcn_s_setprio(0);
        if (more) {
            k0a = nk0a; k0b = nk0b; k1a = nk1a; k1b = nk1b;
            v0 = nv0; v1 = nv1; v2 = nv2; v3 = nv3;
        }
    }

    const int bb = bh >> 4, hh = bh & 15;
    #pragma unroll
    for (int r = 0; r < 4; r++) {
        int q = q0w + ((lane >> 4) << 2) + r;
        float inv = 1.f / srun[r];
        size_t base = ((size_t)bb * 2048 + q) * 1024 + hh * 64;
        #pragma unroll
        for (int dt = 0; dt < 4; dt++) {
            ab[base + dt * 16 + ld16] = (__bf16)(o[dt][r] * inv);
        }
    }
}

// ---------------- launch ----------------
extern "C" void kernel_launch(void* const* d_in, const int* in_sizes, int n_in,
                              void* d_out, int out_size, void* d_ws, size_t ws_size,
                              hipStream_t stream) {
    const float* x = (const float*)d_in[0];
    const float* w_attn = (const float*)d_in[1];
    const float* b_attn = (const float*)d_in[2];
    const float* w_proj = (const float*)d_in[3];
    const float* b_proj = (const float*)d_in[4];

    float* out = (float*)d_out;
    float* present = out + (size_t)2 * 2048 * 1024;

    char* w = (char*)d_ws;
    __bf16* xb   = (__bf16*)(w);
    __bf16* wabt = (__bf16*)(w + 8388608);
    __bf16* wpbt = (__bf16*)(w + 14680064);
    __bf16* qb   = (__bf16*)(w + 16777216);
    __bf16* kb   = (__bf16*)(w + 25165824);
    __bf16* vt   = (__bf16*)(w + 33554432);
    __bf16* ab   = xb;

    cvt_kernel<<<2048, 256, 0, stream>>>(x, xb, 524288);
    tcvt_kernel<<<dim3(48, 16), 256, 0, stream>>>(w_attn, wabt, 1024, 3072);
    tcvt_kernel<<<dim3(16, 16), 256, 0, stream>>>(w_proj, wpbt, 1024, 1024);

    gemm_qkv_kernel<<<dim3(24, 32), 512, 0, stream>>>(xb, wabt, b_attn, qb, kb, vt, present);

    attn_kernel<<<1024, 256, 0, stream>>>(qb, kb, vt, ab);

    gemm_proj_kernel<<<dim3(8, 32), 512, 0, stream>>>(ab, wpbt, b_proj, out);
}